// Round 3
// baseline (148.780 us; speedup 1.0000x reference)
//
#include <hip/hip_runtime.h>

#define ALPHA 0.2f
constexpr int B_   = 64;
constexpr int N_   = 2048;
constexpr int IN_  = 1024;
constexpr int OUT_ = 1024;
constexpr int CHUNK = 128;            // rows per workgroup in main pass
constexpr int NCH   = N_ / CHUNK;     // 16 chunks per batch
constexpr int RPW   = CHUNK / 4;      // 32 rows per wave (4 waves/block)

// ---- workspace layout (float offsets), ~5.3 MB total ----
constexpr size_t WA1   = 0;        // 1024 : W^T a1
constexpr size_t WA2   = 1024;     // 1024 : W^T a2
constexpr size_t E0    = 2048;     // 64   : f[b,0,:].wa1 + wb.a1 + wb.a2
constexpr size_t ZPART = 2112;     // B*NCH = 1024
constexpr size_t PART1 = 4096;     // 128*1024 partials for wa1
constexpr size_t PART2 = 135168;   // 128*1024 partials for wa2
constexpr size_t GPART = 270336;   // B*NCH*IN = 1048576
constexpr size_t GV    = 1318912;  // B*IN = 65536

__device__ inline float wave_reduce_sum(float v) {
    #pragma unroll
    for (int off = 32; off > 0; off >>= 1) v += __shfl_xor(v, off);
    return v;
}

// Partial wa1/wa2: block owns 8 rows of W, threads cover all 1024 cols (float4).
__global__ void kA1(const float* __restrict__ W, const float* __restrict__ aw,
                    float* __restrict__ ws) {
    int t = threadIdx.x, blk = blockIdx.x;   // 128 blocks
    float4 acc1 = make_float4(0.f, 0.f, 0.f, 0.f);
    float4 acc2 = make_float4(0.f, 0.f, 0.f, 0.f);
    #pragma unroll
    for (int r = 0; r < 8; ++r) {
        int d = blk * 8 + r;
        float a1 = aw[d], a2 = aw[OUT_ + d];
        float4 w = ((const float4*)(W + (size_t)d * IN_))[t];
        acc1.x += a1 * w.x; acc1.y += a1 * w.y; acc1.z += a1 * w.z; acc1.w += a1 * w.w;
        acc2.x += a2 * w.x; acc2.y += a2 * w.y; acc2.z += a2 * w.z; acc2.w += a2 * w.w;
    }
    ((float4*)(ws + PART1))[blk * 256 + t] = acc1;
    ((float4*)(ws + PART2))[blk * 256 + t] = acc2;
}

// Reduce 128 partials -> wa1, wa2.
__global__ void kA2(float* __restrict__ ws) {
    int idx = blockIdx.x * 256 + threadIdx.x;   // 8 blocks * 256 = 2048
    int which = idx >> 10, col = idx & 1023;
    const float* p = ws + (which ? PART2 : PART1) + col;
    float s = 0.f;
    #pragma unroll 8
    for (int r = 0; r < 128; ++r) s += p[(size_t)r * 1024];
    ws[(which ? WA2 : WA1) + col] = s;
}

// e0[b] = f[b,0,:].wa1 + wb.a1 + wb.a2   (one block per b)
__global__ void kP(const float* __restrict__ f, const float* __restrict__ wb,
                   const float* __restrict__ aw, float* __restrict__ ws) {
    int b = blockIdx.x, t = threadIdx.x;
    float4 v   = ((const float4*)(f + (size_t)b * N_ * IN_))[t];
    float4 w1  = ((const float4*)(ws + WA1))[t];
    float4 wbv = ((const float4*)wb)[t];
    float4 a1v = ((const float4*)aw)[t];
    float4 a2v = ((const float4*)(aw + OUT_))[t];
    float p = v.x * w1.x + v.y * w1.y + v.z * w1.z + v.w * w1.w
            + wbv.x * (a1v.x + a2v.x) + wbv.y * (a1v.y + a2v.y)
            + wbv.z * (a1v.z + a2v.z) + wbv.w * (a1v.w + a2v.w);
    __shared__ float red[256];
    red[t] = p;
    __syncthreads();
    for (int off = 128; off > 0; off >>= 1) {
        if (t < off) red[t] += red[t + off];
        __syncthreads();
    }
    if (t == 0) ws[E0 + b] = red[0];
}

// Single feature pass: per row n, s=f.wa2, w=exp(leaky(e0+s+ab)),
// accumulate gpart += w*f and zpart += w.   Wave-per-row, reg double-buffer.
__global__ void kMain(const float* __restrict__ f, const float* __restrict__ ab,
                      float* __restrict__ ws) {
    int b = blockIdx.y, chunk = blockIdx.x;
    int t = threadIdx.x, wave = t >> 6, lane = t & 63;
    float cst = ws[E0 + b] + ab[0];

    const float4* wa2_4 = (const float4*)(ws + WA2);
    float4 ra2[4];
    #pragma unroll
    for (int k = 0; k < 4; ++k) ra2[k] = wa2_4[k * 64 + lane];

    const float4* fbase = (const float4*)(f + ((size_t)b * N_ + (size_t)chunk * CHUNK) * IN_);
    float4 acc[4];
    #pragma unroll
    for (int k = 0; k < 4; ++k) acc[k] = make_float4(0.f, 0.f, 0.f, 0.f);
    float z = 0.f;

    float4 v[4], nv[4];
    int r = wave;
    #pragma unroll
    for (int k = 0; k < 4; ++k) v[k] = fbase[(size_t)r * 256 + k * 64 + lane];

    for (int i = 0; i < RPW; ++i) {
        int rn = r + 4;
        if (i + 1 < RPW) {
            #pragma unroll
            for (int k = 0; k < 4; ++k) nv[k] = fbase[(size_t)rn * 256 + k * 64 + lane];
        }
        float dot = 0.f;
        #pragma unroll
        for (int k = 0; k < 4; ++k)
            dot += v[k].x * ra2[k].x + v[k].y * ra2[k].y + v[k].z * ra2[k].z + v[k].w * ra2[k].w;
        dot = wave_reduce_sum(dot);
        float e = dot + cst;
        e = e >= 0.f ? e : ALPHA * e;
        float w = __expf(e);
        z += w;
        #pragma unroll
        for (int k = 0; k < 4; ++k) {
            acc[k].x += w * v[k].x; acc[k].y += w * v[k].y;
            acc[k].z += w * v[k].z; acc[k].w += w * v[k].w;
        }
        if (i + 1 < RPW) {
            #pragma unroll
            for (int k = 0; k < 4; ++k) v[k] = nv[k];
        }
        r = rn;
    }

    __shared__ float4 gbuf[4][256];
    __shared__ float  zbuf[4];
    #pragma unroll
    for (int k = 0; k < 4; ++k) gbuf[wave][k * 64 + lane] = acc[k];
    if (lane == 0) zbuf[wave] = z;
    __syncthreads();
    float4 s0 = gbuf[0][t], s1 = gbuf[1][t], s2 = gbuf[2][t], s3 = gbuf[3][t];
    float4 s = make_float4(s0.x + s1.x + s2.x + s3.x, s0.y + s1.y + s2.y + s3.y,
                           s0.z + s1.z + s2.z + s3.z, s0.w + s1.w + s2.w + s3.w);
    ((float4*)(ws + GPART))[((size_t)b * NCH + chunk) * 256 + t] = s;
    if (t == 0) ws[ZPART + b * NCH + chunk] = zbuf[0] + zbuf[1] + zbuf[2] + zbuf[3];
}

// g[b,:] = (sum_c gpart[b,c,:]) / (sum_c zpart[b,c])
__global__ void kE(float* __restrict__ ws) {
    int b = blockIdx.x, t = threadIdx.x;
    __shared__ float zinv;
    if (t == 0) {
        float zz = 0.f;
        #pragma unroll
        for (int c = 0; c < NCH; ++c) zz += ws[ZPART + b * NCH + c];
        zinv = 1.0f / zz;
    }
    __syncthreads();
    const float4* gp = (const float4*)(ws + GPART);
    float4 acc = make_float4(0.f, 0.f, 0.f, 0.f);
    #pragma unroll
    for (int c = 0; c < NCH; ++c) {
        float4 v = gp[((size_t)b * NCH + c) * 256 + t];
        acc.x += v.x; acc.y += v.y; acc.z += v.z; acc.w += v.w;
    }
    acc.x *= zinv; acc.y *= zinv; acc.z *= zinv; acc.w *= zinv;
    ((float4*)(ws + GV))[b * 256 + t] = acc;
}

// out[b,d] = relu( g[b,:].W[d,:] + w_b[d] + bias_out[d] )
// One wave per d (4 d's per block, 256 blocks); W row held in registers,
// loop over all 64 b reading g from L2. W is fetched from HBM exactly once.
__global__ void kF(const float* __restrict__ W, const float* __restrict__ wb,
                   const float* __restrict__ bias, const float* __restrict__ ws,
                   float* __restrict__ out) {
    int t = threadIdx.x, wave = t >> 6, lane = t & 63;
    int d = blockIdx.x * 4 + wave;
    const float4* w4 = (const float4*)(W + (size_t)d * IN_);
    float4 wreg[4];
    #pragma unroll
    for (int k = 0; k < 4; ++k) wreg[k] = w4[k * 64 + lane];
    float wbb = wb[d] + bias[d];
    const float4* gv = (const float4*)(ws + GV);
    #pragma unroll 4
    for (int b = 0; b < B_; ++b) {
        float acc = 0.f;
        #pragma unroll
        for (int k = 0; k < 4; ++k) {
            float4 g = gv[b * 256 + k * 64 + lane];
            acc += g.x * wreg[k].x + g.y * wreg[k].y + g.z * wreg[k].z + g.w * wreg[k].w;
        }
        acc = wave_reduce_sum(acc);
        if (lane == 0) {
            float p = acc + wbb;
            out[(size_t)b * OUT_ + d] = p > 0.f ? p : 0.f;
        }
    }
}

extern "C" void kernel_launch(void* const* d_in, const int* in_sizes, int n_in,
                              void* d_out, int out_size, void* d_ws, size_t ws_size,
                              hipStream_t stream) {
    const float* f    = (const float*)d_in[0];  // (64,2048,1024)
    const float* W    = (const float*)d_in[1];  // (1024,1024)
    const float* wb   = (const float*)d_in[2];  // (1024,)
    const float* aw   = (const float*)d_in[3];  // (2048,)
    const float* ab   = (const float*)d_in[4];  // scalar
    const float* bias = (const float*)d_in[5];  // (1024,)
    float* out = (float*)d_out;                 // (64,1,1024) f32
    float* ws  = (float*)d_ws;

    kA1<<<dim3(128), 256, 0, stream>>>(W, aw, ws);
    kA2<<<dim3(8), 256, 0, stream>>>(ws);
    kP <<<dim3(B_), 256, 0, stream>>>(f, wb, aw, ws);
    kMain<<<dim3(NCH, B_), 256, 0, stream>>>(f, ab, ws);
    kE <<<dim3(B_), 256, 0, stream>>>(ws);
    kF <<<dim3(OUT_ / 4), 256, 0, stream>>>(W, wb, bias, ws, out);
}

// Round 4
// 129.797 us; speedup vs baseline: 1.1462x; 1.1462x over previous
//
#include <hip/hip_runtime.h>

#define ALPHA 0.2f
constexpr int B_   = 64;
constexpr int N_   = 2048;
constexpr int IN_  = 1024;
constexpr int OUT_ = 1024;
constexpr int CHUNK = 256;            // rows per workgroup in main pass (R2-proven)
constexpr int NCH   = N_ / CHUNK;     // 8 chunks per batch
constexpr int RPW   = CHUNK / 4;      // 64 rows per wave (4 waves/block)

// ---- workspace layout (float offsets), ~3.4 MB total ----
constexpr size_t WA1   = 0;        // 1024 : W^T a1
constexpr size_t WA2   = 1024;     // 1024 : W^T a2
constexpr size_t E0    = 2048;     // 64   : f[b,0,:].wa1 + wb.a1 + wb.a2
constexpr size_t ZPART = 2112;     // B*NCH = 512
constexpr size_t PART1 = 4096;     // 128*1024 partials for wa1
constexpr size_t PART2 = 135168;   // 128*1024 partials for wa2
constexpr size_t GPART = 266240;   // B*NCH*IN = 524288
constexpr size_t GV    = 790528;   // B*IN = 65536

__device__ inline float wave_reduce_sum(float v) {
    #pragma unroll
    for (int off = 32; off > 0; off >>= 1) v += __shfl_xor(v, off);
    return v;
}

// Partial wa1/wa2: block owns 8 rows of W, threads cover all 1024 cols (float4).
__global__ void kW(const float* __restrict__ W, const float* __restrict__ aw,
                   float* __restrict__ ws) {
    int t = threadIdx.x, blk = blockIdx.x;   // 128 blocks
    float4 acc1 = make_float4(0.f, 0.f, 0.f, 0.f);
    float4 acc2 = make_float4(0.f, 0.f, 0.f, 0.f);
    #pragma unroll
    for (int r = 0; r < 8; ++r) {
        int d = blk * 8 + r;
        float a1 = aw[d], a2 = aw[OUT_ + d];
        float4 w = ((const float4*)(W + (size_t)d * IN_))[t];
        acc1.x += a1 * w.x; acc1.y += a1 * w.y; acc1.z += a1 * w.z; acc1.w += a1 * w.w;
        acc2.x += a2 * w.x; acc2.y += a2 * w.y; acc2.z += a2 * w.z; acc2.w += a2 * w.w;
    }
    ((float4*)(ws + PART1))[blk * 256 + t] = acc1;
    ((float4*)(ws + PART2))[blk * 256 + t] = acc2;
}

// Blocks 0..7  : reduce 128 partials -> wa1, wa2 (needed by kMain).
// Blocks 8..71 : e0[b] = f[b,0,:].wa1 + wb.(a1+a2), with the wa1-dot computed
//                directly from the PART1 partials (reassociated, exact in f32 slack).
__global__ void kS(const float* __restrict__ f, const float* __restrict__ wb,
                   const float* __restrict__ aw, float* __restrict__ ws) {
    int t = threadIdx.x;
    if (blockIdx.x < 8) {
        int idx = blockIdx.x * 256 + t;       // 2048 lanes total
        int which = idx >> 10, col = idx & 1023;
        const float* p = ws + (which ? PART2 : PART1) + col;
        float s = 0.f;
        #pragma unroll 8
        for (int r = 0; r < 128; ++r) s += p[(size_t)r * 1024];
        ws[(which ? WA2 : WA1) + col] = s;
    } else {
        int b = blockIdx.x - 8;
        float4 fv = ((const float4*)(f + (size_t)b * N_ * IN_))[t];
        const float4* p1 = (const float4*)(ws + PART1);
        float acc = 0.f;
        #pragma unroll 8
        for (int r = 0; r < 128; ++r) {
            float4 p = p1[(size_t)r * 256 + t];
            acc += fv.x * p.x + fv.y * p.y + fv.z * p.z + fv.w * p.w;
        }
        float4 wbv = ((const float4*)wb)[t];
        float4 a1v = ((const float4*)aw)[t];
        float4 a2v = ((const float4*)(aw + OUT_))[t];
        acc += wbv.x * (a1v.x + a2v.x) + wbv.y * (a1v.y + a2v.y)
             + wbv.z * (a1v.z + a2v.z) + wbv.w * (a1v.w + a2v.w);
        __shared__ float red[256];
        red[t] = acc;
        __syncthreads();
        for (int off = 128; off > 0; off >>= 1) {
            if (t < off) red[t] += red[t + off];
            __syncthreads();
        }
        if (t == 0) ws[E0 + b] = red[0];
    }
}

// Single feature pass: per row n, s=f.wa2, w=exp(leaky(e0+s+ab)),
// accumulate gpart += w*f and zpart += w.   Wave-per-row, reg double-buffer.
__global__ void kMain(const float* __restrict__ f, const float* __restrict__ ab,
                      float* __restrict__ ws) {
    int b = blockIdx.y, chunk = blockIdx.x;
    int t = threadIdx.x, wave = t >> 6, lane = t & 63;
    float cst = ws[E0 + b] + ab[0];

    const float4* wa2_4 = (const float4*)(ws + WA2);
    float4 ra2[4];
    #pragma unroll
    for (int k = 0; k < 4; ++k) ra2[k] = wa2_4[k * 64 + lane];

    const float4* fbase = (const float4*)(f + ((size_t)b * N_ + (size_t)chunk * CHUNK) * IN_);
    float4 acc[4];
    #pragma unroll
    for (int k = 0; k < 4; ++k) acc[k] = make_float4(0.f, 0.f, 0.f, 0.f);
    float z = 0.f;

    float4 v[4], nv[4];
    int r = wave;
    #pragma unroll
    for (int k = 0; k < 4; ++k) v[k] = fbase[(size_t)r * 256 + k * 64 + lane];

    for (int i = 0; i < RPW; ++i) {
        int rn = r + 4;
        if (i + 1 < RPW) {
            #pragma unroll
            for (int k = 0; k < 4; ++k) nv[k] = fbase[(size_t)rn * 256 + k * 64 + lane];
        }
        float dot = 0.f;
        #pragma unroll
        for (int k = 0; k < 4; ++k)
            dot += v[k].x * ra2[k].x + v[k].y * ra2[k].y + v[k].z * ra2[k].z + v[k].w * ra2[k].w;
        dot = wave_reduce_sum(dot);
        float e = dot + cst;
        e = e >= 0.f ? e : ALPHA * e;
        float w = __expf(e);
        z += w;
        #pragma unroll
        for (int k = 0; k < 4; ++k) {
            acc[k].x += w * v[k].x; acc[k].y += w * v[k].y;
            acc[k].z += w * v[k].z; acc[k].w += w * v[k].w;
        }
        if (i + 1 < RPW) {
            #pragma unroll
            for (int k = 0; k < 4; ++k) v[k] = nv[k];
        }
        r = rn;
    }

    __shared__ float4 gbuf[4][256];
    __shared__ float  zbuf[4];
    #pragma unroll
    for (int k = 0; k < 4; ++k) gbuf[wave][k * 64 + lane] = acc[k];
    if (lane == 0) zbuf[wave] = z;
    __syncthreads();
    float4 s0 = gbuf[0][t], s1 = gbuf[1][t], s2 = gbuf[2][t], s3 = gbuf[3][t];
    float4 s = make_float4(s0.x + s1.x + s2.x + s3.x, s0.y + s1.y + s2.y + s3.y,
                           s0.z + s1.z + s2.z + s3.z, s0.w + s1.w + s2.w + s3.w);
    ((float4*)(ws + GPART))[((size_t)b * NCH + chunk) * 256 + t] = s;
    if (t == 0) ws[ZPART + b * NCH + chunk] = zbuf[0] + zbuf[1] + zbuf[2] + zbuf[3];
}

// g[b,:] = (sum_c gpart[b,c,:]) / (sum_c zpart[b,c])
__global__ void kE(float* __restrict__ ws) {
    int b = blockIdx.x, t = threadIdx.x;
    __shared__ float zinv;
    if (t == 0) {
        float zz = 0.f;
        #pragma unroll
        for (int c = 0; c < NCH; ++c) zz += ws[ZPART + b * NCH + c];
        zinv = 1.0f / zz;
    }
    __syncthreads();
    const float4* gp = (const float4*)(ws + GPART);
    float4 acc = make_float4(0.f, 0.f, 0.f, 0.f);
    #pragma unroll
    for (int c = 0; c < NCH; ++c) {
        float4 v = gp[((size_t)b * NCH + c) * 256 + t];
        acc.x += v.x; acc.y += v.y; acc.z += v.z; acc.w += v.w;
    }
    acc.x *= zinv; acc.y *= zinv; acc.z *= zinv; acc.w *= zinv;
    ((float4*)(ws + GV))[b * 256 + t] = acc;
}

// out[b,d] = relu( g[b,:].W[d,:] + w_b[d] + bias_out[d] )
// grid(256,2): block = (4 d's, 32 b's). 512 blocks -> 2 blocks/CU, 2 waves/SIMD.
// W rows live in registers; g read from L2 (64 MB aggregate).
__global__ void kF(const float* __restrict__ W, const float* __restrict__ wb,
                   const float* __restrict__ bias, const float* __restrict__ ws,
                   float* __restrict__ out) {
    int t = threadIdx.x, wave = t >> 6, lane = t & 63;
    int d  = blockIdx.x * 4 + wave;
    int b0 = blockIdx.y * 32;
    const float4* w4 = (const float4*)(W + (size_t)d * IN_);
    float4 wreg[4];
    #pragma unroll
    for (int k = 0; k < 4; ++k) wreg[k] = w4[k * 64 + lane];
    float wbb = wb[d] + bias[d];
    const float4* gv = (const float4*)(ws + GV);
    #pragma unroll 4
    for (int bi = 0; bi < 32; ++bi) {
        int b = b0 + bi;
        float acc = 0.f;
        #pragma unroll
        for (int k = 0; k < 4; ++k) {
            float4 g = gv[b * 256 + k * 64 + lane];
            acc += g.x * wreg[k].x + g.y * wreg[k].y + g.z * wreg[k].z + g.w * wreg[k].w;
        }
        acc = wave_reduce_sum(acc);
        if (lane == 0) {
            float p = acc + wbb;
            out[(size_t)b * OUT_ + d] = p > 0.f ? p : 0.f;
        }
    }
}

extern "C" void kernel_launch(void* const* d_in, const int* in_sizes, int n_in,
                              void* d_out, int out_size, void* d_ws, size_t ws_size,
                              hipStream_t stream) {
    const float* f    = (const float*)d_in[0];  // (64,2048,1024)
    const float* W    = (const float*)d_in[1];  // (1024,1024)
    const float* wb   = (const float*)d_in[2];  // (1024,)
    const float* aw   = (const float*)d_in[3];  // (2048,)
    const float* ab   = (const float*)d_in[4];  // scalar
    const float* bias = (const float*)d_in[5];  // (1024,)
    float* out = (float*)d_out;                 // (64,1,1024) f32
    float* ws  = (float*)d_ws;

    kW   <<<dim3(128), 256, 0, stream>>>(W, aw, ws);
    kS   <<<dim3(8 + B_), 256, 0, stream>>>(f, wb, aw, ws);
    kMain<<<dim3(NCH, B_), 256, 0, stream>>>(f, ab, ws);
    kE   <<<dim3(B_), 256, 0, stream>>>(ws);
    kF   <<<dim3(OUT_ / 4, 2), 256, 0, stream>>>(W, wb, bias, ws, out);
}